// Round 8
// baseline (642.679 us; speedup 1.0000x reference)
//
#include <hip/hip_runtime.h>

#define NHW 15

typedef __bf16 bf16x8 __attribute__((ext_vector_type(8)));
typedef float f32x4 __attribute__((ext_vector_type(4)));
typedef unsigned short u16x8 __attribute__((ext_vector_type(8)));

__device__ __forceinline__ unsigned short f2bf(float f) {
  unsigned x = __float_as_uint(f);
  unsigned r = ((x >> 16) & 1u) + 0x7fffu;  // round-to-nearest-even
  x += r;
  return (unsigned short)(x >> 16);
}

// 2 f32 -> packed 2xbf16 in one instruction (RNE).
__device__ __forceinline__ unsigned cvtpk(float lo, float hi) {
  unsigned r;
  asm("v_cvt_pk_bf16_f32 %0, %1, %2" : "=v"(r) : "v"(lo), "v"(hi));
  return r;
}

// K-permutation for GEMM1: stored col c' <-> original channel c = 64*(c'%8) + c'/8.
// Applied to BOTH xv staging and w_qkv columns; dot product is invariant.
// w_qkv: dst[o][a*8+e] = wq[o][64*e + a].  w_out: unpermuted.
__global__ void convert_weights(const float* __restrict__ wq,
                                const float* __restrict__ wo,
                                unsigned short* __restrict__ dst) {
  int t = blockIdx.x * 256 + threadIdx.x;
  if (t < 98304) {  // 1536 * 64
    int o = t >> 6, a = t & 63;
    const float* src = wq + (size_t)o * 512 + a;
    u16x8 v;
    #pragma unroll
    for (int e = 0; e < 8; ++e) v[e] = f2bf(src[e * 64]);
    *(u16x8*)(dst + (size_t)o * 512 + a * 8) = v;
  } else {          // w_out: 512*512 / 4 per thread
    int i = (t - 98304) * 4;
    float4 v = *(const float4*)(wo + i);
    ushort4 o4;
    o4.x = f2bf(v.x); o4.y = f2bf(v.y); o4.z = f2bf(v.z); o4.w = f2bf(v.w);
    *(ushort4*)(dst + 786432 + i) = o4;
  }
}

// __launch_bounds__(512), NO min-waves arg (r2/(512,4) and r5/(512,2) both
// spilled; r7 at plain (512) = 108 VGPR, no spill).
// Single 80KiB time-shared LDS region -> 2 blocks/CU (163840B = exactly
// 160KiB/CU) -> 4 waves/SIMD. r6/r7's separate regions (145KB) halved
// occupancy; that was the dominant stall (Occ 23%, MfmaUtil 15%).
//
// Parity-class launch: windows with fixed (n%2, w%2) never overlap (stride 4,
// kernel 8). 4 sequential launches; class (0,0) covers every output pixel
// exactly once -> plain stores (do_add=0); others load-add-store.
__launch_bounds__(512)
__global__ void swin_kernel(const float* __restrict__ x,
                            const float* __restrict__ b_out,
                            const unsigned short* __restrict__ wq_all,  // [1536][512] bf16, K-permuted
                            const unsigned short* __restrict__ wo,      // [512][512]  bf16
                            float* __restrict__ res,
                            int n0, int w0, int nN, int nW, int do_add) {
  // single 80KiB region, time-shared (barriers at every phase hand-off):
  //   phase A: xv[64][520] bf16 (66560B)
  //   phase B: 8 x 10240B per-wave attention scratch (81920B)
  //   phase C: att_out[64][520] bf16 (66560B)
  //   phase D: epilogue pixel-major fl[32][517] f32 (66176B)
  __shared__ __align__(16) unsigned short lds0[40960];  // 81920 B

  const int tid  = threadIdx.x;
  const int wave = tid >> 6;
  const int ln   = tid & 63;
  const int rowa = ln & 15;   // A-frag row / B-frag col within 16-tile
  const int kgrp = ln >> 4;   // 0..3 : k-subgroup (8 elems each)
  const int rbase = kgrp * 4; // C/D-layout row base within 16-tile

  const int bid = blockIdx.x;
  const int b  = bid / (nN * nW);
  const int rm = bid % (nN * nW);
  const int n  = n0 + 2 * (rm / nW);
  const int w  = w0 + 2 * (rm % nW);
  const int i0 = n * 4, j0 = w * 4;

  // ---------------- stage patch xv (bf16, K-permuted) ----------------
  // xv'[l][pos*8+e] = x[b, i0+pos/8, j0+pos%8, 8l+e]
  // Prefetch ALL 16 float4 loads first (one HBM latency), then pack+write.
  {
    const float* src = x + (((size_t)(b * 64 + i0)) * 64 + j0 + wave) * 512 + 8 * ln;
    float4 v0[8], v1[8];
    #pragma unroll
    for (int r = 0; r < 8; ++r) {
      v0[r] = *(const float4*)(src + (size_t)r * 32768);      // row stride 64*512
      v1[r] = *(const float4*)(src + (size_t)r * 32768 + 4);
    }
    #pragma unroll
    for (int r = 0; r < 8; ++r) {
      uint4 pk;
      pk.x = cvtpk(v0[r].x, v0[r].y);
      pk.y = cvtpk(v0[r].z, v0[r].w);
      pk.z = cvtpk(v1[r].x, v1[r].y);
      pk.w = cvtpk(v1[r].z, v1[r].w);
      *(uint4*)(lds0 + ln * 520 + (r * 8 + wave) * 8) = pk;
    }
  }
  __syncthreads();

  // ---------------- GEMM1: qkv = xv @ W^T (3 steps; wave owns head `wave`) ----
  // 1-deep software pipeline on the global B-frag loads.
  unsigned qp[4][4][2], kp[4][4][2], vp[4][4][2];  // packed bf16 pairs (rows 2p,2p+1)
  {
    auto step = [&](int O, unsigned (&dst)[4][4][2]) {
      f32x4 acc[4][4];
      #pragma unroll
      for (int i = 0; i < 4; ++i)
        #pragma unroll
        for (int j = 0; j < 4; ++j) acc[i][j] = (f32x4){0.f, 0.f, 0.f, 0.f};
      const unsigned short* wb = wq_all + (size_t)O * 512 + (size_t)rowa * 512 + kgrp * 8;
      bf16x8 bfr[4];
      #pragma unroll
      for (int nt = 0; nt < 4; ++nt)
        bfr[nt] = *(const bf16x8*)(wb + (size_t)nt * 8192);  // ks=0
      #pragma unroll 2
      for (int ks = 0; ks < 16; ++ks) {
        bf16x8 bn[4];
        if (ks < 15) {
          #pragma unroll
          for (int nt = 0; nt < 4; ++nt)
            bn[nt] = *(const bf16x8*)(wb + (size_t)nt * 8192 + (ks + 1) * 32);
        }
        bf16x8 a[4];
        #pragma unroll
        for (int mt = 0; mt < 4; ++mt)
          a[mt] = *(const bf16x8*)(lds0 + (mt * 16 + rowa) * 520 + ks * 32 + kgrp * 8);
        #pragma unroll
        for (int nt = 0; nt < 4; ++nt)
          #pragma unroll
          for (int mt = 0; mt < 4; ++mt)
            acc[mt][nt] = __builtin_amdgcn_mfma_f32_16x16x32_bf16(a[mt], bfr[nt], acc[mt][nt], 0, 0, 0);
        if (ks < 15) {
          #pragma unroll
          for (int nt = 0; nt < 4; ++nt) bfr[nt] = bn[nt];
        }
      }
      #pragma unroll
      for (int mt = 0; mt < 4; ++mt)
        #pragma unroll
        for (int nt = 0; nt < 4; ++nt)
          #pragma unroll
          for (int p = 0; p < 2; ++p)
            dst[mt][nt][p] = cvtpk(acc[mt][nt][2 * p], acc[mt][nt][2 * p + 1]);
    };
    step(wave * 64,        qp);
    step(512 + wave * 64,  kp);
    step(1024 + wave * 64, vp);
  }
  __syncthreads();  // xv dead; per-wave scratch overlays lds0

  // ---------------- attention: head = wave, all private -------------
  unsigned short* qsc = lds0 + wave * 5120;  // 64 x 40 bf16 rows (80B, 16B aligned)
  unsigned short* ksc = qsc + 2560;

  f32x4 dt_[4][4];
  #pragma unroll
  for (int i = 0; i < 4; ++i)
    #pragma unroll
    for (int j = 0; j < 4; ++j) dt_[i][j] = (f32x4){0.f, 0.f, 0.f, 0.f};

  #pragma unroll
  for (int h2 = 0; h2 < 2; ++h2) {  // d-half of K=64
    #pragma unroll
    for (int mt = 0; mt < 4; ++mt)
      #pragma unroll
      for (int cc = 0; cc < 2; ++cc) {
        int ct = 2 * h2 + cc;
        #pragma unroll
        for (int p = 0; p < 2; ++p) {
          unsigned uq = qp[mt][ct][p];
          unsigned uk = kp[mt][ct][p];
          int rr = mt * 16 + rbase + 2 * p;
          int dd = cc * 16 + rowa;
          qsc[rr * 40 + dd]       = (unsigned short)uq;
          qsc[(rr + 1) * 40 + dd] = (unsigned short)(uq >> 16);
          ksc[rr * 40 + dd]       = (unsigned short)uk;
          ksc[(rr + 1) * 40 + dd] = (unsigned short)(uk >> 16);
        }
      }
    bf16x8 aq[4];
    #pragma unroll
    for (int mt = 0; mt < 4; ++mt)
      aq[mt] = *(const bf16x8*)(qsc + (mt * 16 + rowa) * 40 + kgrp * 8);
    #pragma unroll
    for (int nt = 0; nt < 4; ++nt) {
      bf16x8 bk = *(const bf16x8*)(ksc + (nt * 16 + rowa) * 40 + kgrp * 8);
      #pragma unroll
      for (int mt = 0; mt < 4; ++mt)
        dt_[mt][nt] = __builtin_amdgcn_mfma_f32_16x16x32_bf16(aq[mt], bk, dt_[mt][nt], 0, 0, 0);
    }
  }

  // softmax (scale = hd^-0.5 = 1/8); per-row constant bias drops out exactly
  const float SC = 0.125f * 1.44269504088896f;
  float rsum[4][4];
  #pragma unroll
  for (int mt = 0; mt < 4; ++mt)
    #pragma unroll
    for (int j = 0; j < 4; ++j) {
      float m = dt_[mt][0][j];
      #pragma unroll
      for (int nt = 1; nt < 4; ++nt) m = fmaxf(m, dt_[mt][nt][j]);
      #pragma unroll
      for (int s = 1; s < 16; s <<= 1) m = fmaxf(m, __shfl_xor(m, s, 64));
      float sum = 0.f;
      #pragma unroll
      for (int nt = 0; nt < 4; ++nt) {
        float p = exp2f((dt_[mt][nt][j] - m) * SC);
        dt_[mt][nt][j] = p;
        sum += p;
      }
      #pragma unroll
      for (int s = 1; s < 16; s <<= 1) sum += __shfl_xor(sum, s, 64);
      rsum[mt][j] = sum;
    }

  // PV: out_h = P @ v  (stage P and v^T per m-half; same-wave scratch reuse)
  unsigned short* Psc  = qsc;
  unsigned short* vTsc = ksc;
  f32x4 oat[4][4];
  #pragma unroll
  for (int i = 0; i < 4; ++i)
    #pragma unroll
    for (int j = 0; j < 4; ++j) oat[i][j] = (f32x4){0.f, 0.f, 0.f, 0.f};

  #pragma unroll
  for (int mh = 0; mh < 2; ++mh) {
    #pragma unroll
    for (int mt = 0; mt < 4; ++mt)
      #pragma unroll
      for (int cc = 0; cc < 2; ++cc) {
        int ct = 2 * mh + cc;
        #pragma unroll
        for (int j = 0; j < 4; ++j)
          Psc[(mt * 16 + rbase + j) * 40 + cc * 16 + rowa] = f2bf(dt_[mt][ct][j]);
      }
    #pragma unroll
    for (int mm = 0; mm < 2; ++mm) {
      int mtm = 2 * mh + mm;
      #pragma unroll
      for (int ct = 0; ct < 4; ++ct)
        #pragma unroll
        for (int p = 0; p < 2; ++p) {
          unsigned u = vp[mtm][ct][p];
          int m_ = mm * 16 + rbase + 2 * p;
          int d  = ct * 16 + rowa;
          *(unsigned*)(vTsc + d * 40 + m_) = u;  // two adjacent m' -> one b32 write
        }
    }
    bf16x8 ap[4];
    #pragma unroll
    for (int mt = 0; mt < 4; ++mt)
      ap[mt] = *(const bf16x8*)(Psc + (mt * 16 + rowa) * 40 + kgrp * 8);
    #pragma unroll
    for (int dtt = 0; dtt < 4; ++dtt) {
      bf16x8 bv = *(const bf16x8*)(vTsc + (dtt * 16 + rowa) * 40 + kgrp * 8);
      #pragma unroll
      for (int mt = 0; mt < 4; ++mt)
        oat[mt][dtt] = __builtin_amdgcn_mfma_f32_16x16x32_bf16(ap[mt], bv, oat[mt][dtt], 0, 0, 0);
    }
  }

  __syncthreads();  // all waves done with private scratch before att_out overlay

  // normalize + stage att_out (cols [wave*64, wave*64+64)) into lds0
  #pragma unroll
  for (int mt = 0; mt < 4; ++mt)
    #pragma unroll
    for (int j = 0; j < 4; ++j) {
      float inv = 1.f / rsum[mt][j];
      #pragma unroll
      for (int dtt = 0; dtt < 4; ++dtt)
        lds0[(mt * 16 + rbase + j) * 520 + wave * 64 + dtt * 16 + rowa] =
            f2bf(oat[mt][dtt][j] * inv);
    }
  __syncthreads();

  // ---------------- GEMM2: out2 = att_out @ w_out^T + b_out ----------
  f32x4 a2[4][4];
  #pragma unroll
  for (int i = 0; i < 4; ++i)
    #pragma unroll
    for (int j = 0; j < 4; ++j) a2[i][j] = (f32x4){0.f, 0.f, 0.f, 0.f};
  {
    const unsigned short* wb = wo + (size_t)(wave * 64 + rowa) * 512 + kgrp * 8;
    bf16x8 bw[4];
    #pragma unroll
    for (int nt = 0; nt < 4; ++nt)
      bw[nt] = *(const bf16x8*)(wb + (size_t)nt * 8192);  // ks=0
    #pragma unroll 2
    for (int ks = 0; ks < 16; ++ks) {
      bf16x8 bn[4];
      if (ks < 15) {
        #pragma unroll
        for (int nt = 0; nt < 4; ++nt)
          bn[nt] = *(const bf16x8*)(wb + (size_t)nt * 8192 + (ks + 1) * 32);
      }
      bf16x8 a[4];
      #pragma unroll
      for (int mt = 0; mt < 4; ++mt)
        a[mt] = *(const bf16x8*)(lds0 + (mt * 16 + rowa) * 520 + ks * 32 + kgrp * 8);
      #pragma unroll
      for (int nt = 0; nt < 4; ++nt)
        #pragma unroll
        for (int mt = 0; mt < 4; ++mt)
          a2[mt][nt] = __builtin_amdgcn_mfma_f32_16x16x32_bf16(a[mt], bw[nt], a2[mt][nt], 0, 0, 0);
      if (ks < 15) {
        #pragma unroll
        for (int nt = 0; nt < 4; ++nt) bw[nt] = bn[nt];
      }
    }
  }

  float bias[4];
  #pragma unroll
  for (int nt = 0; nt < 4; ++nt) bias[nt] = b_out[wave * 64 + nt * 16 + rowa];

  __syncthreads();  // att_out reads done before fl overlay

  // ---------------- epilogue: LDS un-scramble + NON-ATOMIC write ----
  // value (l = mt*16+kgrp*4+j, o = wave*64+nt*16+rowa):
  //   pixel p = nt*16+rowa, channel ch = l*8 + wave.
  // Phase ph covers p in [32ph, 32ph+32): stage fl[p-32ph][ch] f32 (stride 517),
  // then wave-contiguous 1KB reads -> float4 store (or load-add-store).
  float* fl = (float*)lds0;  // [32][517] f32 = 66176 B
  #pragma unroll
  for (int ph = 0; ph < 2; ++ph) {
    if (ph) __syncthreads();  // phase-0 reads done before rewrite
    #pragma unroll
    for (int nt2 = 0; nt2 < 2; ++nt2) {
      int nt = 2 * ph + nt2;
      int prow = nt2 * 16 + rowa;
      #pragma unroll
      for (int mt = 0; mt < 4; ++mt)
        #pragma unroll
        for (int j = 0; j < 4; ++j) {
          int ch = (mt * 16 + rbase + j) * 8 + wave;
          fl[prow * 517 + ch] = a2[mt][nt][j] + bias[nt];
        }
    }
    __syncthreads();
    #pragma unroll
    for (int it = 0; it < 8; ++it) {
      int idx = it * 512 + tid;        // float4 index in [0,4096)
      int pp  = idx >> 7;              // local pixel 0..31
      int c4  = (idx & 127) << 2;      // channel 0..508
      float4 v = *(const float4*)(fl + pp * 517 + c4);
      int p  = ph * 32 + pp;
      int gh = i0 + (p >> 3), gw = j0 + (p & 7);
      float* dst = res + (((size_t)(b * 64 + gh)) * 64 + gw) * 512 + c4;
      if (do_add) {
        float4 old = *(const float4*)dst;
        v.x += old.x; v.y += old.y; v.z += old.z; v.w += old.w;
      }
      *(float4*)dst = v;
    }
  }
}

extern "C" void kernel_launch(void* const* d_in, const int* in_sizes, int n_in,
                              void* d_out, int out_size, void* d_ws, size_t ws_size,
                              hipStream_t stream) {
  const float* x      = (const float*)d_in[0];
  const float* w_qkv  = (const float*)d_in[1];
  const float* w_out  = (const float*)d_in[2];
  const float* b_out  = (const float*)d_in[3];
  // d_in[4], d_in[5] (rel_h, rel_w): per-query-row constant bias is softmax-invariant -> unused
  float* res = (float*)d_out;
  unsigned short* wbf = (unsigned short*)d_ws;  // [0,2MB) weights bf16

  convert_weights<<<640, 256, 0, stream>>>(w_qkv, w_out, wbf);

  // 4 parity classes; class (0,0) first with plain stores (covers every output
  // element exactly once -> no memset needed), remaining classes accumulate.
  const int cls[4][5] = {
      {0, 0, 8, 8, 0},  // n even, w even: 512 blocks, store
      {0, 1, 8, 7, 1},  // n even, w odd : 448 blocks, add
      {1, 0, 7, 8, 1},  // n odd,  w even: 448 blocks, add
      {1, 1, 7, 7, 1},  // n odd,  w odd : 392 blocks, add
  };
  for (int c = 0; c < 4; ++c) {
    int nblk = 8 * cls[c][2] * cls[c][3];
    swin_kernel<<<nblk, 512, 0, stream>>>(x, b_out, wbf, wbf + 786432, res,
                                          cls[c][0], cls[c][1], cls[c][2],
                                          cls[c][3], cls[c][4]);
  }
}

// Round 10
// 380.726 us; speedup vs baseline: 1.6880x; 1.6880x over previous
//
#include <hip/hip_runtime.h>

#define NHW 15

typedef __bf16 bf16x8 __attribute__((ext_vector_type(8)));
typedef float f32x4 __attribute__((ext_vector_type(4)));
typedef unsigned short u16x8 __attribute__((ext_vector_type(8)));

__device__ __forceinline__ unsigned short f2bf(float f) {
  unsigned x = __float_as_uint(f);
  unsigned r = ((x >> 16) & 1u) + 0x7fffu;  // round-to-nearest-even
  x += r;
  return (unsigned short)(x >> 16);
}

// 2 f32 -> packed 2xbf16 in one instruction (RNE).
__device__ __forceinline__ unsigned cvtpk(float lo, float hi) {
  unsigned r;
  asm("v_cvt_pk_bf16_f32 %0, %1, %2" : "=v"(r) : "v"(lo), "v"(hi));
  return r;
}

// Fragment-ordered bf16 weights: one wave b-frag load = contiguous 1KB.
// wq (K-permuted: c' = a*8+e <-> orig c = 64e+a):
//   dst[(((g*16+ks)*4+nt)*64+lane)*8+e] = wq[g*64+nt*16+(lane&15)][64e + ks*4+(lane>>4)]
// wo (natural K order), at +786432:
//   dst[...same idx...] = wo[g*64+nt*16+(lane&15)][ks*32+(lane>>4)*8+e]
__global__ void convert_weights(const float* __restrict__ wq,
                                const float* __restrict__ wo,
                                unsigned short* __restrict__ dst) {
  int t = blockIdx.x * 256 + threadIdx.x;  // [0, 131072)
  if (t < 98304) {  // wq: g<24
    int lane = t & 63, nt = (t >> 6) & 3, ks = (t >> 8) & 15, g = t >> 12;
    int o = g * 64 + nt * 16 + (lane & 15);
    int a = ks * 4 + (lane >> 4);
    const float* src = wq + (size_t)o * 512 + a;
    u16x8 v;
    #pragma unroll
    for (int e = 0; e < 8; ++e) v[e] = f2bf(src[e * 64]);
    *(u16x8*)(dst + (size_t)t * 8) = v;
  } else {          // wo: g<8
    int u = t - 98304;
    int lane = u & 63, nt = (u >> 6) & 3, ks = (u >> 8) & 15, g = u >> 12;
    int o = g * 64 + nt * 16 + (lane & 15);
    int c0 = ks * 32 + (lane >> 4) * 8;
    const float* src = wo + (size_t)o * 512 + c0;
    float4 v0 = *(const float4*)(src);
    float4 v1 = *(const float4*)(src + 4);
    u16x8 pk;
    pk[0] = f2bf(v0.x); pk[1] = f2bf(v0.y); pk[2] = f2bf(v0.z); pk[3] = f2bf(v0.w);
    pk[4] = f2bf(v1.x); pk[5] = f2bf(v1.y); pk[6] = f2bf(v1.z); pk[7] = f2bf(v1.w);
    *(u16x8*)(dst + 786432 + (size_t)u * 8) = pk;
  }
}

// Registers: unified VGPR+AGPR ~170-225 -> 2 waves/SIMD tier (129-256); this
// is the occupancy wall (AGPRs count, rocprof VGPR_Count doesn't show them).
// Spill tripwire: per-launch WRITE_SIZE must stay ~65.5MB.
//
// Parity-class launch: windows with fixed (n%2, w%2) never overlap (stride 4,
// kernel 8). 4 sequential launches; class (0,0) covers every output pixel
// exactly once -> plain stores (do_add=0); others load-add-store.
__launch_bounds__(512)
__global__ void swin_kernel(const float* __restrict__ x,
                            const float* __restrict__ b_out,
                            const unsigned short* __restrict__ wq_all,  // frag-ordered
                            const unsigned short* __restrict__ wo,      // frag-ordered
                            float* __restrict__ res,
                            int n0, int w0, int nN, int nW, int do_add) {
  // single 80KiB region, time-shared:
  //   phase A: xv[64][520] bf16 (66560B)
  //   phase B: 8 x 10240B per-wave scratch (q/k halves, then P/vT,
  //            then O[64] rows with STRIDE 72 u16 (64 cols live; 4608<=5120))
  //   phase C: epilogue pixel-major fl[32][517] f32 (66176B)
  __shared__ __align__(16) unsigned short lds0[40960];  // 81920 B

  const int tid  = threadIdx.x;
  const int wave = tid >> 6;
  const int ln   = tid & 63;
  const int rowa = ln & 15;   // A-frag row / B-frag col within 16-tile
  const int kgrp = ln >> 4;   // 0..3 : k-subgroup (8 elems each)
  const int rbase = kgrp * 4; // C/D-layout row base within 16-tile

  const int bid = blockIdx.x;
  const int b  = bid / (nN * nW);
  const int rm = bid % (nN * nW);
  const int n  = n0 + 2 * (rm / nW);
  const int w  = w0 + 2 * (rm % nW);
  const int i0 = n * 4, j0 = w * 4;

  // ---------------- stage patch xv (bf16, K-permuted) ----------------
  // xv'[l][pos*8+e] = x[b, i0+pos/8, j0+pos%8, 8l+e]
  {
    const float* src = x + (((size_t)(b * 64 + i0)) * 64 + j0 + wave) * 512 + 8 * ln;
    float4 v0[8], v1[8];
    #pragma unroll
    for (int r = 0; r < 8; ++r) {
      v0[r] = *(const float4*)(src + (size_t)r * 32768);      // row stride 64*512
      v1[r] = *(const float4*)(src + (size_t)r * 32768 + 4);
    }
    #pragma unroll
    for (int r = 0; r < 8; ++r) {
      uint4 pk;
      pk.x = cvtpk(v0[r].x, v0[r].y);
      pk.y = cvtpk(v0[r].z, v0[r].w);
      pk.z = cvtpk(v1[r].x, v1[r].y);
      pk.w = cvtpk(v1[r].z, v1[r].w);
      *(uint4*)(lds0 + ln * 520 + (r * 8 + wave) * 8) = pk;
    }
  }
  __syncthreads();

  // ---------------- GEMM1: qkv = xv @ W^T (3 steps; wave owns head `wave`) ----
  // Frag-ordered weights: load = contiguous 1KB/wave-instr; 2-deep prefetch.
  unsigned qp[4][4][2], kp[4][4][2], vp[4][4][2];  // packed bf16 pairs (rows 2p,2p+1)
  {
    auto step = [&](int g, unsigned (&dst)[4][4][2]) {
      f32x4 acc[4][4];
      #pragma unroll
      for (int i = 0; i < 4; ++i)
        #pragma unroll
        for (int j = 0; j < 4; ++j) acc[i][j] = (f32x4){0.f, 0.f, 0.f, 0.f};
      const unsigned short* wb = wq_all + (size_t)g * 32768 + ln * 8;
      bf16x8 b0[4], b1[4];
      #pragma unroll
      for (int nt = 0; nt < 4; ++nt) b0[nt] = *(const bf16x8*)(wb + (0 * 4 + nt) * 512);
      #pragma unroll
      for (int nt = 0; nt < 4; ++nt) b1[nt] = *(const bf16x8*)(wb + (1 * 4 + nt) * 512);
      #pragma unroll 1
      for (int ks2 = 0; ks2 < 8; ++ks2) {
        bf16x8 bn0[4], bn1[4];
        if (ks2 < 7) {
          #pragma unroll
          for (int nt = 0; nt < 4; ++nt)
            bn0[nt] = *(const bf16x8*)(wb + ((2 * ks2 + 2) * 4 + nt) * 512);
          #pragma unroll
          for (int nt = 0; nt < 4; ++nt)
            bn1[nt] = *(const bf16x8*)(wb + ((2 * ks2 + 3) * 4 + nt) * 512);
        }
        bf16x8 a[4];
        #pragma unroll
        for (int mt = 0; mt < 4; ++mt)
          a[mt] = *(const bf16x8*)(lds0 + (mt * 16 + rowa) * 520 + (2 * ks2) * 32 + kgrp * 8);
        __builtin_amdgcn_s_setprio(1);
        #pragma unroll
        for (int nt = 0; nt < 4; ++nt)
          #pragma unroll
          for (int mt = 0; mt < 4; ++mt)
            acc[mt][nt] = __builtin_amdgcn_mfma_f32_16x16x32_bf16(a[mt], b0[nt], acc[mt][nt], 0, 0, 0);
        __builtin_amdgcn_s_setprio(0);
        #pragma unroll
        for (int mt = 0; mt < 4; ++mt)
          a[mt] = *(const bf16x8*)(lds0 + (mt * 16 + rowa) * 520 + (2 * ks2 + 1) * 32 + kgrp * 8);
        __builtin_amdgcn_s_setprio(1);
        #pragma unroll
        for (int nt = 0; nt < 4; ++nt)
          #pragma unroll
          for (int mt = 0; mt < 4; ++mt)
            acc[mt][nt] = __builtin_amdgcn_mfma_f32_16x16x32_bf16(a[mt], b1[nt], acc[mt][nt], 0, 0, 0);
        __builtin_amdgcn_s_setprio(0);
        if (ks2 < 7) {
          #pragma unroll
          for (int nt = 0; nt < 4; ++nt) { b0[nt] = bn0[nt]; b1[nt] = bn1[nt]; }
        }
      }
      #pragma unroll
      for (int mt = 0; mt < 4; ++mt)
        #pragma unroll
        for (int nt = 0; nt < 4; ++nt)
          #pragma unroll
          for (int p = 0; p < 2; ++p)
            dst[mt][nt][p] = cvtpk(acc[mt][nt][2 * p], acc[mt][nt][2 * p + 1]);
    };
    step(wave,      qp);
    step(8 + wave,  kp);
    step(16 + wave, vp);
  }
  __syncthreads();  // xv dead; per-wave scratch overlays lds0

  // ---------------- attention: head = wave, all private -------------
  unsigned short* qsc = lds0 + wave * 5120;  // 64 x 40 bf16 rows (80B, 16B aligned)
  unsigned short* ksc = qsc + 2560;

  f32x4 dt_[4][4];
  #pragma unroll
  for (int i = 0; i < 4; ++i)
    #pragma unroll
    for (int j = 0; j < 4; ++j) dt_[i][j] = (f32x4){0.f, 0.f, 0.f, 0.f};

  #pragma unroll
  for (int h2 = 0; h2 < 2; ++h2) {  // d-half of K=64
    #pragma unroll
    for (int mt = 0; mt < 4; ++mt)
      #pragma unroll
      for (int cc = 0; cc < 2; ++cc) {
        int ct = 2 * h2 + cc;
        #pragma unroll
        for (int p = 0; p < 2; ++p) {
          unsigned uq = qp[mt][ct][p];
          unsigned uk = kp[mt][ct][p];
          int rr = mt * 16 + rbase + 2 * p;
          int dd = cc * 16 + rowa;
          qsc[rr * 40 + dd]       = (unsigned short)uq;
          qsc[(rr + 1) * 40 + dd] = (unsigned short)(uq >> 16);
          ksc[rr * 40 + dd]       = (unsigned short)uk;
          ksc[(rr + 1) * 40 + dd] = (unsigned short)(uk >> 16);
        }
      }
    bf16x8 aq[4];
    #pragma unroll
    for (int mt = 0; mt < 4; ++mt)
      aq[mt] = *(const bf16x8*)(qsc + (mt * 16 + rowa) * 40 + kgrp * 8);
    __builtin_amdgcn_s_setprio(1);
    #pragma unroll
    for (int nt = 0; nt < 4; ++nt) {
      bf16x8 bk = *(const bf16x8*)(ksc + (nt * 16 + rowa) * 40 + kgrp * 8);
      #pragma unroll
      for (int mt = 0; mt < 4; ++mt)
        dt_[mt][nt] = __builtin_amdgcn_mfma_f32_16x16x32_bf16(aq[mt], bk, dt_[mt][nt], 0, 0, 0);
    }
    __builtin_amdgcn_s_setprio(0);
  }

  // softmax (scale = hd^-0.5 = 1/8); per-row constant bias drops out exactly
  const float SC = 0.125f * 1.44269504088896f;
  float rsum[4][4];
  #pragma unroll
  for (int mt = 0; mt < 4; ++mt)
    #pragma unroll
    for (int j = 0; j < 4; ++j) {
      float m = dt_[mt][0][j];
      #pragma unroll
      for (int nt = 1; nt < 4; ++nt) m = fmaxf(m, dt_[mt][nt][j]);
      #pragma unroll
      for (int s = 1; s < 16; s <<= 1) m = fmaxf(m, __shfl_xor(m, s, 64));
      float sum = 0.f;
      #pragma unroll
      for (int nt = 0; nt < 4; ++nt) {
        float p = exp2f((dt_[mt][nt][j] - m) * SC);
        dt_[mt][nt][j] = p;
        sum += p;
      }
      #pragma unroll
      for (int s = 1; s < 16; s <<= 1) sum += __shfl_xor(sum, s, 64);
      rsum[mt][j] = sum;
    }

  // PV: out_h = P @ v  (stage P and v^T per m-half; same-wave scratch reuse)
  unsigned short* Psc  = qsc;
  unsigned short* vTsc = ksc;
  f32x4 oat[4][4];
  #pragma unroll
  for (int i = 0; i < 4; ++i)
    #pragma unroll
    for (int j = 0; j < 4; ++j) oat[i][j] = (f32x4){0.f, 0.f, 0.f, 0.f};

  #pragma unroll
  for (int mh = 0; mh < 2; ++mh) {
    #pragma unroll
    for (int mt = 0; mt < 4; ++mt)
      #pragma unroll
      for (int cc = 0; cc < 2; ++cc) {
        int ct = 2 * mh + cc;
        #pragma unroll
        for (int j = 0; j < 4; ++j)
          Psc[(mt * 16 + rbase + j) * 40 + cc * 16 + rowa] = f2bf(dt_[mt][ct][j]);
      }
    #pragma unroll
    for (int mm = 0; mm < 2; ++mm) {
      int mtm = 2 * mh + mm;
      #pragma unroll
      for (int ct = 0; ct < 4; ++ct)
        #pragma unroll
        for (int p = 0; p < 2; ++p) {
          unsigned u = vp[mtm][ct][p];
          int m_ = mm * 16 + rbase + 2 * p;
          int d  = ct * 16 + rowa;
          *(unsigned*)(vTsc + d * 40 + m_) = u;  // two adjacent m' -> one b32 write
        }
    }
    bf16x8 ap[4];
    #pragma unroll
    for (int mt = 0; mt < 4; ++mt)
      ap[mt] = *(const bf16x8*)(Psc + (mt * 16 + rowa) * 40 + kgrp * 8);
    __builtin_amdgcn_s_setprio(1);
    #pragma unroll
    for (int dtt = 0; dtt < 4; ++dtt) {
      bf16x8 bv = *(const bf16x8*)(vTsc + (dtt * 16 + rowa) * 40 + kgrp * 8);
      #pragma unroll
      for (int mt = 0; mt < 4; ++mt)
        oat[mt][dtt] = __builtin_amdgcn_mfma_f32_16x16x32_bf16(ap[mt], bv, oat[mt][dtt], 0, 0, 0);
    }
    __builtin_amdgcn_s_setprio(0);
  }

  // normalize + write O[64 rows, STRIDE 72] into OWN scratch (P/vT dead;
  // 64*72=4608 <= 5120 u16 per-wave region; cols d = 0..63 live).
  // GEMM2 reads all 8 waves' O regions directly -> no att_out repack.
  #pragma unroll
  for (int mt = 0; mt < 4; ++mt)
    #pragma unroll
    for (int j = 0; j < 4; ++j) {
      float inv = 1.f / rsum[mt][j];
      int l = mt * 16 + rbase + j;
      #pragma unroll
      for (int dtt = 0; dtt < 4; ++dtt)
        qsc[l * 72 + dtt * 16 + rowa] = f2bf(oat[mt][dtt][j] * inv);
    }
  __syncthreads();

  // ---------------- GEMM2: out2 = att @ w_out^T + b_out ----------
  // K-step ks: att cols c = ks*32 + kgrp*8 + e -> head h = ks>>1 (uniform),
  // within-head d = (ks&1)*32 + kgrp*8 + e. A from wave h's O scratch
  // (stride 72). B from frag-ordered wo with 2-deep prefetch.
  f32x4 a2[4][4];
  #pragma unroll
  for (int i = 0; i < 4; ++i)
    #pragma unroll
    for (int j = 0; j < 4; ++j) a2[i][j] = (f32x4){0.f, 0.f, 0.f, 0.f};
  {
    const unsigned short* wb = wo + (size_t)wave * 32768 + ln * 8;
    bf16x8 b0[4], b1[4];
    #pragma unroll
    for (int nt = 0; nt < 4; ++nt) b0[nt] = *(const bf16x8*)(wb + (0 * 4 + nt) * 512);
    #pragma unroll
    for (int nt = 0; nt < 4; ++nt) b1[nt] = *(const bf16x8*)(wb + (1 * 4 + nt) * 512);
    #pragma unroll 1
    for (int ks2 = 0; ks2 < 8; ++ks2) {
      bf16x8 bn0[4], bn1[4];
      if (ks2 < 7) {
        #pragma unroll
        for (int nt = 0; nt < 4; ++nt)
          bn0[nt] = *(const bf16x8*)(wb + ((2 * ks2 + 2) * 4 + nt) * 512);
        #pragma unroll
        for (int nt = 0; nt < 4; ++nt)
          bn1[nt] = *(const bf16x8*)(wb + ((2 * ks2 + 3) * 4 + nt) * 512);
      }
      // ks = 2*ks2 (head ks2, d 0..31), ks+1 (head ks2, d 32..63)
      bf16x8 a[4];
      #pragma unroll
      for (int mt = 0; mt < 4; ++mt)
        a[mt] = *(const bf16x8*)(lds0 + ks2 * 5120 + (mt * 16 + rowa) * 72 + kgrp * 8);
      __builtin_amdgcn_s_setprio(1);
      #pragma unroll
      for (int nt = 0; nt < 4; ++nt)
        #pragma unroll
        for (int mt = 0; mt < 4; ++mt)
          a2[mt][nt] = __builtin_amdgcn_mfma_f32_16x16x32_bf16(a[mt], b0[nt], a2[mt][nt], 0, 0, 0);
      __builtin_amdgcn_s_setprio(0);
      #pragma unroll
      for (int mt = 0; mt < 4; ++mt)
        a[mt] = *(const bf16x8*)(lds0 + ks2 * 5120 + (mt * 16 + rowa) * 72 + 32 + kgrp * 8);
      __builtin_amdgcn_s_setprio(1);
      #pragma unroll
      for (int nt = 0; nt < 4; ++nt)
        #pragma unroll
        for (int mt = 0; mt < 4; ++mt)
          a2[mt][nt] = __builtin_amdgcn_mfma_f32_16x16x32_bf16(a[mt], b1[nt], a2[mt][nt], 0, 0, 0);
      __builtin_amdgcn_s_setprio(0);
      if (ks2 < 7) {
        #pragma unroll
        for (int nt = 0; nt < 4; ++nt) { b0[nt] = bn0[nt]; b1[nt] = bn1[nt]; }
      }
    }
  }

  float bias[4];
  #pragma unroll
  for (int nt = 0; nt < 4; ++nt) bias[nt] = b_out[wave * 64 + nt * 16 + rowa];

  __syncthreads();  // scratch reads done before fl overlay

  // ---------------- epilogue: LDS un-scramble + NON-ATOMIC write ----
  // value (l = mt*16+kgrp*4+j, o = wave*64+nt*16+rowa):
  //   pixel p = nt*16+rowa, channel ch = l*8 + wave.
  // Phase ph covers p in [32ph, 32ph+32): stage fl[p-32ph][ch] f32 (stride 517),
  // then wave-contiguous 1KB reads -> float4 store (or load-add-store).
  float* fl = (float*)lds0;  // [32][517] f32 = 66176 B
  #pragma unroll
  for (int ph = 0; ph < 2; ++ph) {
    if (ph) __syncthreads();  // phase-0 reads done before rewrite
    #pragma unroll
    for (int nt2 = 0; nt2 < 2; ++nt2) {
      int nt = 2 * ph + nt2;
      int prow = nt2 * 16 + rowa;
      #pragma unroll
      for (int mt = 0; mt < 4; ++mt)
        #pragma unroll
        for (int j = 0; j < 4; ++j) {
          int ch = (mt * 16 + rbase + j) * 8 + wave;
          fl[prow * 517 + ch] = a2[mt][nt][j] + bias[nt];
        }
    }
    __syncthreads();
    #pragma unroll
    for (int it = 0; it < 8; ++it) {
      int idx = it * 512 + tid;        // float4 index in [0,4096)
      int pp  = idx >> 7;              // local pixel 0..31
      int c4  = (idx & 127) << 2;      // channel 0..508
      float4 v = *(const float4*)(fl + pp * 517 + c4);
      int p  = ph * 32 + pp;
      int gh = i0 + (p >> 3), gw = j0 + (p & 7);
      float* dst = res + (((size_t)(b * 64 + gh)) * 64 + gw) * 512 + c4;
      if (do_add) {
        float4 old = *(const float4*)dst;
        v.x += old.x; v.y += old.y; v.z += old.z; v.w += old.w;
      }
      *(float4*)dst = v;
    }
  }
}

extern "C" void kernel_launch(void* const* d_in, const int* in_sizes, int n_in,
                              void* d_out, int out_size, void* d_ws, size_t ws_size,
                              hipStream_t stream) {
  const float* x      = (const float*)d_in[0];
  const float* w_qkv  = (const float*)d_in[1];
  const float* w_out  = (const float*)d_in[2];
  const float* b_out  = (const float*)d_in[3];
  // d_in[4], d_in[5] (rel_h, rel_w): per-query-row constant bias is softmax-invariant -> unused
  float* res = (float*)d_out;
  unsigned short* wbf = (unsigned short*)d_ws;  // [0,2MB) frag-ordered weights bf16

  convert_weights<<<512, 256, 0, stream>>>(w_qkv, w_out, wbf);

  // 4 parity classes; class (0,0) first with plain stores (covers every output
  // element exactly once -> no memset needed), remaining classes accumulate.
  const int cls[4][5] = {
      {0, 0, 8, 8, 0},  // n even, w even: 512 blocks, store
      {0, 1, 8, 7, 1},  // n even, w odd : 448 blocks, add
      {1, 0, 7, 8, 1},  // n odd,  w even: 448 blocks, add
      {1, 1, 7, 7, 1},  // n odd,  w odd : 392 blocks, add
  };
  for (int c = 0; c < 4; ++c) {
    int nblk = 8 * cls[c][2] * cls[c][3];
    swin_kernel<<<nblk, 512, 0, stream>>>(x, b_out, wbf, wbf + 786432, res,
                                          cls[c][0], cls[c][1], cls[c][2],
                                          cls[c][3], cls[c][4]);
  }
}